// Round 14
// baseline (89.195 us; speedup 1.0000x reference)
//
#include <hip/hip_runtime.h>

#define BB 4
#define CC 256
#define HH 48
#define WW 48
#define HWHW 2304
#define KK 49
#define RELN 128

// ws layout (floats): q | k | v | sbuf | WT
// q,k,v channel-packed: [b][c/4][h][w][4]
#define QSZ (BB*CC*HWHW)            // 2359296 floats per tensor
#define ATTNOFF (3*QSZ)             // sbuf: [B][H][64][W] (taps 0-48, qx 49-55, qy 56-62)
#define SBUF_FLOATS (BB*HH*64*WW)   // 589824
#define WTOFF (ATTNOFF + SBUF_FLOATS)
// XT (bf16 hi/lo of x, PRE-SWIZZLED chunks) lives in d_out

typedef short bf16x8 __attribute__((ext_vector_type(8)));
typedef float f32x4 __attribute__((ext_vector_type(4)));

__device__ __forceinline__ void split_bf16(float f, unsigned short& hi, unsigned short& lo)
{
    unsigned u = __float_as_uint(f);
    hi = (unsigned short)(u >> 16);
    float r = f - __uint_as_float(u & 0xFFFF0000u);
    unsigned v = __float_as_uint(r);
    v += 0x7FFFu + ((v >> 16) & 1u);
    lo = (unsigned short)(v >> 16);
}

__device__ __forceinline__ void gload16(const uint4* g, uint4* l)
{
    __builtin_amdgcn_global_load_lds(
        (const __attribute__((address_space(1))) void*)g,
        (__attribute__((address_space(3))) void*)l, 16, 0, 0);
}

// ---------------- prep: zero sbuf | convert x -> XT | convert w -> WT ----------------
__global__ __launch_bounds__(256) void prep_kernel(
    const float* __restrict__ x,
    const float* __restrict__ wq, const float* __restrict__ wk,
    const float* __restrict__ wvp,
    unsigned short* __restrict__ xt, unsigned short* __restrict__ wt,
    float* __restrict__ ws)
{
    __shared__ unsigned short lds[32*520];
    const int bid = blockIdx.x;
    const int t = threadIdx.x;

    if (bid < 576) {                       // zero sbuf (atomics target)
        float4* p = (float4*)(ws + ATTNOFF);
        p[bid*256 + t] = make_float4(0.f,0.f,0.f,0.f);
        return;
    }
    if (bid < 864) {                       // convert_x, 288 blocks
        const int bid2 = bid - 576;
        const int b = bid2 / 72;
        const int hw0 = (bid2 % 72) * 32;
        const int hw = t & 31, cp = t >> 5;
        #pragma unroll 4
        for (int i = 0; i < 32; ++i) {
            int c = i*8 + cp;
            float f = x[((size_t)b*CC + c)*HWHW + hw0 + hw];
            unsigned short hi, lo; split_bf16(f, hi, lo);
            int ch = i*2;
            lds[hw*520 + ((ch       ^ (hw&7))*8) + cp] = hi;
            lds[hw*520 + (((ch + 1) ^ (hw&7))*8) + cp] = lo;
        }
        __syncthreads();
        const int hw2 = t >> 3, u = t & 7;
        uint4* xt4 = (uint4*)xt;
        const size_t rowbase = ((size_t)b*HWHW + hw0 + hw2) * 64;
        #pragma unroll
        for (int j = 0; j < 8; ++j) {
            int chunk = j*8 + u;
            uint4 v = *(const uint4*)&lds[hw2*520 + chunk*8];
            xt4[rowbase + chunk] = v;
        }
        return;
    }
    {                                       // convert_w, 96 blocks
        const int tt = (bid - 864)*256 + t;
        const int m = tt >> 5, kg = tt & 31;
        const float* src = (m < 256) ? wq : (m < 512) ? wk : wvp;
        const float* row = src + (size_t)(m & 255)*256 + kg*8;
        unsigned short h[8], l[8];
        #pragma unroll
        for (int j = 0; j < 8; ++j) split_bf16(row[j], h[j], l[j]);
        uint4 hv, lv;
        hv.x = (unsigned)h[0] | ((unsigned)h[1]<<16); hv.y = (unsigned)h[2] | ((unsigned)h[3]<<16);
        hv.z = (unsigned)h[4] | ((unsigned)h[5]<<16); hv.w = (unsigned)h[6] | ((unsigned)h[7]<<16);
        lv.x = (unsigned)l[0] | ((unsigned)l[1]<<16); lv.y = (unsigned)l[2] | ((unsigned)l[3]<<16);
        lv.z = (unsigned)l[4] | ((unsigned)l[5]<<16); lv.w = (unsigned)l[6] | ((unsigned)l[7]<<16);
        uint4* dstrow = (uint4*)wt + (size_t)m*64;
        const int ks = kg >> 2, s_hi = 2*(kg & 3);
        dstrow[ks*8 + ( s_hi      ^ (m&7))] = hv;
        dstrow[ks*8 + ((s_hi + 1) ^ (m&7))] = lv;
    }
}

// ---------------- Projection GEMM (unchanged from R12: counted-vmcnt dbuf) ----------------
__global__ __launch_bounds__(256) void proj_gemm_kernel(
    const unsigned short* __restrict__ xt,
    const unsigned short* __restrict__ wt,
    float* __restrict__ ws)
{
    __shared__ uint4 smem[2][1024];
    const int n0 = blockIdx.x * 64;
    const int m0 = blockIdx.y * 64;
    const int b = n0 / HWHW;
    const int hwb = n0 % HWHW;
    const int tid = threadIdx.x;
    const int wid = tid >> 6, ln = tid & 63;
    const int wm = wid >> 1, wn = wid & 1;
    const int l15 = ln & 15, g = ln >> 4;

    f32x4 acc[2][2];
    #pragma unroll
    for (int i = 0; i < 2; ++i)
        #pragma unroll
        for (int j = 0; j < 2; ++j) acc[i][j] = (f32x4){0.f,0.f,0.f,0.f};

    const uint4* wt4 = (const uint4*)wt;
    const uint4* xt4 = (const uint4*)xt;
    const int lrow = ln >> 3, lslot = ln & 7;

    #define STAGE(bf, ks)                                                          \
        {                                                                          \
            _Pragma("unroll")                                                      \
            for (int i = 0; i < 2; ++i) {                                          \
                int seg = wid*2 + i;                                               \
                int row = seg*8 + lrow;                                            \
                gload16(wt4 + (size_t)(m0 + row)*64 + (ks)*8 + lslot,              \
                        &smem[bf][seg*64]);                                        \
                gload16(xt4 + (size_t)(n0 + row)*64 + (ks)*8 + lslot,              \
                        &smem[bf][512 + seg*64]);                                  \
            }                                                                      \
        }

    STAGE(0, 0);
    #pragma unroll
    for (int ks = 0; ks < 8; ++ks) {
        const int cur = ks & 1;
        if (ks < 7) STAGE(cur ^ 1, ks + 1);
        if (ks < 7) asm volatile("s_waitcnt vmcnt(4)" ::: "memory");
        else        asm volatile("s_waitcnt vmcnt(0)" ::: "memory");
        __builtin_amdgcn_s_barrier();
        __builtin_amdgcn_sched_barrier(0);
        bf16x8 aH[2], aL[2], bH[2], bL[2];
        #pragma unroll
        for (int mt = 0; mt < 2; ++mt) {
            int rA = wm*32 + mt*16 + l15;
            aH[mt] = *(const bf16x8*)&smem[cur][rA*8 + ((2*g)   ^ (rA&7))];
            aL[mt] = *(const bf16x8*)&smem[cur][rA*8 + ((2*g+1) ^ (rA&7))];
        }
        #pragma unroll
        for (int nt = 0; nt < 2; ++nt) {
            int rB = wn*32 + nt*16 + l15;
            bH[nt] = *(const bf16x8*)&smem[cur][512 + rB*8 + ((2*g)   ^ (rB&7))];
            bL[nt] = *(const bf16x8*)&smem[cur][512 + rB*8 + ((2*g+1) ^ (rB&7))];
        }
        #pragma unroll
        for (int mt = 0; mt < 2; ++mt)
            #pragma unroll
            for (int nt = 0; nt < 2; ++nt) {
                acc[mt][nt] = __builtin_amdgcn_mfma_f32_16x16x32_bf16(aH[mt], bH[nt], acc[mt][nt], 0, 0, 0);
                acc[mt][nt] = __builtin_amdgcn_mfma_f32_16x16x32_bf16(aH[mt], bL[nt], acc[mt][nt], 0, 0, 0);
                acc[mt][nt] = __builtin_amdgcn_mfma_f32_16x16x32_bf16(aL[mt], bH[nt], acc[mt][nt], 0, 0, 0);
            }
        if (ks < 7) {
            asm volatile("s_waitcnt lgkmcnt(0)" ::: "memory");
            __builtin_amdgcn_s_barrier();
        }
    }
    #undef STAGE

    const int proj = m0 >> 8;
    #pragma unroll
    for (int mt = 0; mt < 2; ++mt) {
        int chb = (m0 & 255) + wm*32 + mt*16 + 4*g;
        int ch4 = chb >> 2;
        #pragma unroll
        for (int nt = 0; nt < 2; ++nt) {
            int hw = hwb + wn*32 + nt*16 + l15;
            float* dst = ws + (size_t)proj*QSZ + (((size_t)b*64 + ch4)*HWHW + hw)*4;
            *(f32x4*)dst = acc[mt][nt];
        }
    }
}

// ---------------- Scores v5: cg16 split (3072 blocks), q hoisted, 1 barrier ----------------
// block = (b, h, cg16 of 16 channels = 4 packed groups); LDS 12.5 KB -> 8 blocks/CU.
// q loads issued FIRST (latency overlaps k staging + barrier). atomicAdd to sbuf.
__global__ __launch_bounds__(256) void scores_partial_kernel(
    const float* __restrict__ relx,
    const float* __restrict__ rely,
    float* __restrict__ ws)
{
    const float* qbuf = ws;
    const float* kbuf = ws + QSZ;
    float* sbuf = ws + ATTNOFF;

    __shared__ float ks[4][7][56][4];   // 12544 B

    const int bid = blockIdx.x;
    const int cg16 = bid & 15;          // 16-channel group
    const int h  = (bid >> 4) % HH;
    const int b  = bid / (16*HH);

    const int tid = threadIdx.x;
    const int wv = tid >> 6;
    const int w = tid & 63;
    const bool act = (w < WW);
    const int cq0 = cg16*4;             // first packed group

    // hoist q loads: issue before staging so L2 latency overlaps it
    f32x4 q4[4];
    #pragma unroll
    for (int ci4 = 0; ci4 < 4; ++ci4)
        q4[ci4] = act ? *(const f32x4*)(qbuf + (((size_t)b*64 + cq0 + ci4)*HWHW + h*WW + w)*4)
                      : (f32x4){0.f,0.f,0.f,0.f};

    // stage 4 packed groups x 7 rows x 54 cols of k (zero OOB)
    #pragma unroll
    for (int t = 0; t < 6; ++t) {
        int fi = tid + t*256;
        if (fi < 1512) {
            int ci4 = fi / 378;
            int rem = fi - ci4*378;
            int rw = rem / 54;
            int cl = rem - rw*54;
            int gr = h + rw - 3;
            int gc = cl - 3;
            float4 v = make_float4(0.f,0.f,0.f,0.f);
            if (gr >= 0 && gr < HH && gc >= 0 && gc < WW)
                v = *(const float4*)(kbuf
                    + (((size_t)b*64 + cq0 + ci4)*HWHW + gr*WW + gc)*4);
            *(float4*)&ks[ci4][rw][cl][0] = v;
        }
    }
    __syncthreads();

    float s[14];
    #pragma unroll
    for (int i=0;i<14;i++) s[i]=0.f;

    const float* rel = (cg16 < 8) ? relx : rely;
    const int relch0 = (cg16 < 8) ? 0 : RELN;

    if (act) {
        #pragma unroll
        for (int ci4 = 0; ci4 < 4; ++ci4) {
            const float qa[4] = {q4[ci4][0], q4[ci4][1], q4[ci4][2], q4[ci4][3]};
            if (wv < 3) {
                #pragma unroll
                for (int dd = 0; dd < 2; ++dd) {
                    const int row = wv*2 + dd;
                    #pragma unroll
                    for (int dl = 0; dl < 7; ++dl) {
                        const float4 kv = *(const float4*)&ks[ci4][row][w + dl][0];
                        s[dd*7+dl] += qa[0]*kv.x + qa[1]*kv.y + qa[2]*kv.z + qa[3]*kv.w;
                    }
                }
            } else {
                #pragma unroll
                for (int dl = 0; dl < 7; ++dl) {
                    const float4 kv = *(const float4*)&ks[ci4][6][w + dl][0];
                    s[dl] += qa[0]*kv.x + qa[1]*kv.y + qa[2]*kv.z + qa[3]*kv.w;
                }
                #pragma unroll
                for (int cc = 0; cc < 4; ++cc) {
                    const int ch = (cq0 + ci4)*4 + cc;
                    const float* rp = rel + (ch - relch0)*7;
                    #pragma unroll
                    for (int l = 0; l < 7; ++l)
                        s[7+l] += qa[cc] * rp[l];
                }
            }
        }
        float* base = sbuf + ((size_t)(b*HH + h)*64)*WW + w;
        if (wv < 3) {
            #pragma unroll
            for (int i = 0; i < 14; ++i)
                atomicAdd(base + (size_t)(wv*14 + i)*WW, s[i]);
        } else {
            #pragma unroll
            for (int i = 0; i < 7; ++i)
                atomicAdd(base + (size_t)(42 + i)*WW, s[i]);
            const int slot0 = (cg16 < 8) ? 49 : 56;
            #pragma unroll
            for (int l = 0; l < 7; ++l)
                atomicAdd(base + (size_t)(slot0 + l)*WW, s[7+l]);
        }
    }
}

// ---------------- Softmax finalize (in place on sbuf) ----------------
__global__ __launch_bounds__(64) void softmax_kernel(float* __restrict__ ws)
{
    float* sbuf = ws + ATTNOFF;
    const int p = blockIdx.x*64 + threadIdx.x;
    const int w = p % WW;
    const int h = (p / WW) % HH;
    const int b = p / (WW*HH);
    float* base = sbuf + ((size_t)(b*HH + h)*64)*WW + w;

    float tot[KK], qx[7], qy[7];
    #pragma unroll
    for (int i=0;i<KK;i++) tot[i] = base[(size_t)i*WW];
    #pragma unroll
    for (int l=0;l<7;l++) { qx[l] = base[(size_t)(49+l)*WW]; qy[l] = base[(size_t)(56+l)*WW]; }

    float mx = -1e30f;
    #pragma unroll
    for (int dk=0;dk<7;dk++) {
        #pragma unroll
        for (int dl=0;dl<7;dl++) {
            tot[dk*7+dl] += qy[dk] + qx[dl];
            mx = fmaxf(mx, tot[dk*7+dl]);
        }
    }
    float sum = 0.f;
    #pragma unroll
    for (int i=0;i<KK;i++) { float e = __expf(tot[i]-mx); tot[i]=e; sum += e; }
    float inv = 1.f/sum;
    #pragma unroll
    for (int i=0;i<KK;i++) base[(size_t)i*WW] = tot[i]*inv;
}

// ---------------- PV + bias (R12 version: global attn reads, 4px sliding window) ----------------
__global__ __launch_bounds__(128) void pv_kernel(
    const float* __restrict__ bias,
    const float* __restrict__ ws,
    float* __restrict__ out)
{
    const float* vbuf = ws + 2*QSZ;
    const float* attn = ws + ATTNOFF;

    const int bid = blockIdx.x;
    const int pxt = bid % 18;
    const int pgq = (bid / 18) % 16;
    const int b   = bid / (18*16);

    const int tid = threadIdx.x;
    const int pxg = tid & 31;
    const int pg  = pgq*4 + (tid >> 5);

    const int hw0 = pxt*128 + pxg*4;
    const int w0 = hw0 % WW;
    const int h0 = hw0 / WW;

    const float* vb = vbuf + ((size_t)b*64 + pg)*HWHW*4;
    const float* ab = attn + ((size_t)(b*HH + h0)*64)*WW;

    const float4 b4 = *(const float4*)(bias + pg*4);
    f32x4 bias4 = (f32x4){b4.x, b4.y, b4.z, b4.w};
    f32x4 acc[4];
    #pragma unroll
    for (int p = 0; p < 4; ++p) acc[p] = bias4;

    #pragma unroll
    for (int dk = 0; dk < 7; ++dk) {
        const int gr = h0 + dk - 3;
        const bool rok = (gr >= 0 && gr < HH);
        f32x4 vrow[10];
        #pragma unroll
        for (int jj = 0; jj < 10; ++jj) {
            const int gc = w0 - 3 + jj;
            vrow[jj] = (rok && gc >= 0 && gc < WW)
                ? *(const f32x4*)(vb + ((size_t)gr*WW + gc)*4)
                : (f32x4){0.f,0.f,0.f,0.f};
        }
        const float* arow = ab + (size_t)(dk*7)*WW + w0;
        #pragma unroll
        for (int dl = 0; dl < 7; ++dl) {
            const float4 av = *(const float4*)(arow + (size_t)dl*WW);
            acc[0] += vrow[dl+0] * av.x;
            acc[1] += vrow[dl+1] * av.y;
            acc[2] += vrow[dl+2] * av.z;
            acc[3] += vrow[dl+3] * av.w;
        }
    }
    #pragma unroll
    for (int c = 0; c < 4; ++c) {
        float4 o;
        o.x = acc[0][c]; o.y = acc[1][c]; o.z = acc[2][c]; o.w = acc[3][c];
        *(float4*)(out + ((size_t)b*CC + pg*4 + c)*HWHW + hw0) = o;
    }
}

extern "C" void kernel_launch(void* const* d_in, const int* in_sizes, int n_in,
                              void* d_out, int out_size, void* d_ws, size_t ws_size,
                              hipStream_t stream) {
    const float* x    = (const float*)d_in[0];
    const float* wq   = (const float*)d_in[1];
    const float* wk   = (const float*)d_in[2];
    const float* wv   = (const float*)d_in[3];
    const float* bias = (const float*)d_in[4];
    const float* relx = (const float*)d_in[5];
    const float* rely = (const float*)d_in[6];
    float* ws  = (float*)d_ws;
    float* out = (float*)d_out;
    unsigned short* xt = (unsigned short*)d_out;
    unsigned short* wt = (unsigned short*)(ws + WTOFF);

    prep_kernel<<<dim3(960), dim3(256), 0, stream>>>(x, wq, wk, wv, xt, wt, ws);
    proj_gemm_kernel<<<dim3(144, 12), dim3(256), 0, stream>>>(xt, wt, ws);
    scores_partial_kernel<<<dim3(BB*HH*16), dim3(256), 0, stream>>>(relx, rely, ws);
    softmax_kernel<<<dim3(144), dim3(64), 0, stream>>>(ws);
    pv_kernel<<<dim3(BB*16*18), dim3(128), 0, stream>>>(bias, ws, out);
}

// Round 15
// 75.152 us; speedup vs baseline: 1.1869x; 1.1869x over previous
//
#include <hip/hip_runtime.h>

#define BB 4
#define CC 256
#define HH 48
#define WW 48
#define HWHW 2304
#define KK 49
#define RELN 128

// ws float offsets: QB(bf16,swz) | (free) | v f32 | sbuf | WT | KB(bf16,swz) | RB
#define QSZ (BB*CC*HWHW)            // 2359296 floats
#define ATTNOFF (3*QSZ)             // sbuf: [B*H][64][48] taps 0..48
#define SBUF_FLOATS (BB*HH*64*WW)
#define WTOFF (ATTNOFF + SBUF_FLOATS)
#define WT_FLOATS 196608
#define KBOFF (WTOFF + WT_FLOATS)   // KB: 4b*8ck*48h*64row*64u16 = 3145728 floats
#define KB_FLOATS 3145728
#define RBOFF (KBOFF + KB_FLOATS)   // RB: 2rel*4ck*16l*64u16 = 4096 floats
// XT (bf16 hi/lo of x, pre-swizzled) lives in d_out

typedef short bf16x8 __attribute__((ext_vector_type(8)));
typedef float f32x4 __attribute__((ext_vector_type(4)));

__device__ __forceinline__ void split_bf16(float f, unsigned short& hi, unsigned short& lo)
{
    unsigned u = __float_as_uint(f);
    hi = (unsigned short)(u >> 16);
    float r = f - __uint_as_float(u & 0xFFFF0000u);
    unsigned v = __float_as_uint(r);
    v += 0x7FFFu + ((v >> 16) & 1u);
    lo = (unsigned short)(v >> 16);
}

__device__ __forceinline__ void gload16(const uint4* g, uint4* l)
{
    __builtin_amdgcn_global_load_lds(
        (const __attribute__((address_space(1))) void*)g,
        (__attribute__((address_space(3))) void*)l, 16, 0, 0);
}

// ---- prep: convert x->XT | w->WT | zero KB | build RB ----
__global__ __launch_bounds__(256) void prep_kernel(
    const float* __restrict__ x,
    const float* __restrict__ wq, const float* __restrict__ wk,
    const float* __restrict__ wvp,
    const float* __restrict__ relx, const float* __restrict__ rely,
    unsigned short* __restrict__ xt, unsigned short* __restrict__ wt,
    float* __restrict__ ws)
{
    __shared__ unsigned short lds[32*520];
    const int bid = blockIdx.x;
    const int t = threadIdx.x;

    if (bid < 288) {                       // convert_x
        const int b = bid / 72;
        const int hw0 = (bid % 72) * 32;
        const int hw = t & 31, cp = t >> 5;
        #pragma unroll 4
        for (int i = 0; i < 32; ++i) {
            int c = i*8 + cp;
            float f = x[((size_t)b*CC + c)*HWHW + hw0 + hw];
            unsigned short hi, lo; split_bf16(f, hi, lo);
            int ch = i*2;
            lds[hw*520 + ((ch       ^ (hw&7))*8) + cp] = hi;
            lds[hw*520 + (((ch + 1) ^ (hw&7))*8) + cp] = lo;
        }
        __syncthreads();
        const int hw2 = t >> 3, u = t & 7;
        uint4* xt4 = (uint4*)xt;
        const size_t rowbase = ((size_t)b*HWHW + hw0 + hw2) * 64;
        #pragma unroll
        for (int j = 0; j < 8; ++j) {
            int chunk = j*8 + u;
            uint4 v = *(const uint4*)&lds[hw2*520 + chunk*8];
            xt4[rowbase + chunk] = v;
        }
        return;
    }
    if (bid < 384) {                       // convert_w
        const int tt = (bid - 288)*256 + t;
        const int m = tt >> 5, kg = tt & 31;
        const float* src = (m < 256) ? wq : (m < 512) ? wk : wvp;
        const float* row = src + (size_t)(m & 255)*256 + kg*8;
        unsigned short h[8], l[8];
        #pragma unroll
        for (int j = 0; j < 8; ++j) split_bf16(row[j], h[j], l[j]);
        uint4 hv, lv;
        hv.x = (unsigned)h[0] | ((unsigned)h[1]<<16); hv.y = (unsigned)h[2] | ((unsigned)h[3]<<16);
        hv.z = (unsigned)h[4] | ((unsigned)h[5]<<16); hv.w = (unsigned)h[6] | ((unsigned)h[7]<<16);
        lv.x = (unsigned)l[0] | ((unsigned)l[1]<<16); lv.y = (unsigned)l[2] | ((unsigned)l[3]<<16);
        lv.z = (unsigned)l[4] | ((unsigned)l[5]<<16); lv.w = (unsigned)l[6] | ((unsigned)l[7]<<16);
        uint4* dstrow = (uint4*)wt + (size_t)m*64;
        const int ks = kg >> 2, s_hi = 2*(kg & 3);
        dstrow[ks*8 + ( s_hi      ^ (m&7))] = hv;
        dstrow[ks*8 + ((s_hi + 1) ^ (m&7))] = lv;
        return;
    }
    if (bid < 1152) {                      // zero KB (pads must be exact 0)
        f32x4* kbz = (f32x4*)(ws + KBOFF);
        int i0 = (bid - 384)*256 + t;      // 0..196607
        f32x4 z = (f32x4){0.f,0.f,0.f,0.f};
        #pragma unroll
        for (int it = 0; it < 4; ++it) kbz[i0 + it*196608] = z;
        return;
    }
    {                                       // RB: rel tables, bf16 hi/lo, swizzled
        unsigned short* rb = (unsigned short*)(ws + RBOFF);
        #pragma unroll
        for (int it = 0; it < 4; ++it) {
            int idx = t + it*256;          // 0..1023 granule-writes
            int gi  = idx & 7;
            int l   = (idx >> 3) & 15;
            int ck4 = (idx >> 7) & 3;
            int rel = idx >> 9;
            int isLo = gi >> 2, g4i = gi & 3;
            unsigned short vals[8];
            #pragma unroll
            for (int j = 0; j < 8; ++j) {
                int cl = ck4*32 + g4i*8 + j;       // 0..127
                float f = (l < 7) ? (rel ? rely[cl*7 + l] : relx[cl*7 + l]) : 0.f;
                unsigned short hi, lo; split_bf16(f, hi, lo);
                vals[j] = isLo ? lo : hi;
            }
            int slot = gi ^ (l & 7);
            unsigned short* dst = rb + (((size_t)rel*4 + ck4)*16 + l)*64 + slot*8;
            uint4 pack;
            pack.x = (unsigned)vals[0] | ((unsigned)vals[1]<<16);
            pack.y = (unsigned)vals[2] | ((unsigned)vals[3]<<16);
            pack.z = (unsigned)vals[4] | ((unsigned)vals[5]<<16);
            pack.w = (unsigned)vals[6] | ((unsigned)vals[7]<<16);
            *(uint4*)dst = pack;
        }
    }
}

// ---- Projection GEMM: q,k -> bf16 QB/KB (swizzled); v -> f32 packed ----
__global__ __launch_bounds__(256) void proj_gemm_kernel(
    const unsigned short* __restrict__ xt,
    const unsigned short* __restrict__ wt,
    float* __restrict__ ws)
{
    __shared__ uint4 smem[2][1024];
    const int n0 = blockIdx.x * 64;
    const int m0 = blockIdx.y * 64;
    const int b = n0 / HWHW;
    const int hwb = n0 % HWHW;
    const int tid = threadIdx.x;
    const int wid = tid >> 6, ln = tid & 63;
    const int wm = wid >> 1, wn = wid & 1;
    const int l15 = ln & 15, g = ln >> 4;

    f32x4 acc[2][2];
    #pragma unroll
    for (int i = 0; i < 2; ++i)
        #pragma unroll
        for (int j = 0; j < 2; ++j) acc[i][j] = (f32x4){0.f,0.f,0.f,0.f};

    const uint4* wt4 = (const uint4*)wt;
    const uint4* xt4 = (const uint4*)xt;
    const int lrow = ln >> 3, lslot = ln & 7;

    #define STAGE(bf, ks)                                                          \
        {                                                                          \
            _Pragma("unroll")                                                      \
            for (int i = 0; i < 2; ++i) {                                          \
                int seg = wid*2 + i;                                               \
                int row = seg*8 + lrow;                                            \
                gload16(wt4 + (size_t)(m0 + row)*64 + (ks)*8 + lslot,              \
                        &smem[bf][seg*64]);                                        \
                gload16(xt4 + (size_t)(n0 + row)*64 + (ks)*8 + lslot,              \
                        &smem[bf][512 + seg*64]);                                  \
            }                                                                      \
        }

    STAGE(0, 0);
    #pragma unroll
    for (int ks = 0; ks < 8; ++ks) {
        const int cur = ks & 1;
        if (ks < 7) STAGE(cur ^ 1, ks + 1);
        if (ks < 7) asm volatile("s_waitcnt vmcnt(4)" ::: "memory");
        else        asm volatile("s_waitcnt vmcnt(0)" ::: "memory");
        __builtin_amdgcn_s_barrier();
        __builtin_amdgcn_sched_barrier(0);
        bf16x8 aH[2], aL[2], bH[2], bL[2];
        #pragma unroll
        for (int mt = 0; mt < 2; ++mt) {
            int rA = wm*32 + mt*16 + l15;
            aH[mt] = *(const bf16x8*)&smem[cur][rA*8 + ((2*g)   ^ (rA&7))];
            aL[mt] = *(const bf16x8*)&smem[cur][rA*8 + ((2*g+1) ^ (rA&7))];
        }
        #pragma unroll
        for (int nt = 0; nt < 2; ++nt) {
            int rB = wn*32 + nt*16 + l15;
            bH[nt] = *(const bf16x8*)&smem[cur][512 + rB*8 + ((2*g)   ^ (rB&7))];
            bL[nt] = *(const bf16x8*)&smem[cur][512 + rB*8 + ((2*g+1) ^ (rB&7))];
        }
        #pragma unroll
        for (int mt = 0; mt < 2; ++mt)
            #pragma unroll
            for (int nt = 0; nt < 2; ++nt) {
                acc[mt][nt] = __builtin_amdgcn_mfma_f32_16x16x32_bf16(aH[mt], bH[nt], acc[mt][nt], 0, 0, 0);
                acc[mt][nt] = __builtin_amdgcn_mfma_f32_16x16x32_bf16(aH[mt], bL[nt], acc[mt][nt], 0, 0, 0);
                acc[mt][nt] = __builtin_amdgcn_mfma_f32_16x16x32_bf16(aL[mt], bH[nt], acc[mt][nt], 0, 0, 0);
            }
        if (ks < 7) {
            asm volatile("s_waitcnt lgkmcnt(0)" ::: "memory");
            __builtin_amdgcn_s_barrier();
        }
    }
    #undef STAGE

    const int proj = m0 >> 8;
    #pragma unroll
    for (int mt = 0; mt < 2; ++mt) {
        int chb = (m0 & 255) + wm*32 + mt*16 + 4*g;
        #pragma unroll
        for (int nt = 0; nt < 2; ++nt) {
            int hw = hwb + wn*32 + nt*16 + l15;
            f32x4 v = acc[mt][nt];
            if (proj == 2) {
                int ch4 = chb >> 2;
                float* dst = ws + (size_t)2*QSZ + (((size_t)b*64 + ch4)*HWHW + hw)*4;
                *(f32x4*)dst = v;
            } else {
                int hh = hw / 48, w = hw % 48;
                int ck = chb >> 5, p = chb & 31;
                unsigned short h0,h1,h2,h3,l0,l1,l2,l3;
                split_bf16(v[0],h0,l0); split_bf16(v[1],h1,l1);
                split_bf16(v[2],h2,l2); split_bf16(v[3],h3,l3);
                uint2 hv, lv;
                hv.x = (unsigned)h0 | ((unsigned)h1<<16); hv.y = (unsigned)h2 | ((unsigned)h3<<16);
                lv.x = (unsigned)l0 | ((unsigned)l1<<16); lv.y = (unsigned)l2 | ((unsigned)l3<<16);
                int g8 = p >> 3, half = (p >> 2) & 1;
                unsigned short* tb; size_t rowbase; int key;
                if (proj == 0) {
                    tb = (unsigned short*)ws;
                    rowbase = ((((size_t)b*8 + ck)*48 + hh)*48 + w)*64;
                    key = w & 7;
                } else {
                    tb = (unsigned short*)(ws + KBOFF);
                    rowbase = ((((size_t)b*8 + ck)*48 + hh)*64 + (w+3))*64;
                    key = (w+3) & 7;
                }
                *(uint2*)(tb + rowbase + ((g8 ^ key)*8 + half*4))     = hv;
                *(uint2*)(tb + rowbase + (((g8+4) ^ key)*8 + half*4)) = lv;
            }
        }
    }
}

// ---- scores2: banded MFMA + band extraction + fused softmax ----
// block = (b,h), 8 waves: wave dk = 0..6 band MFMAs, wave7 rel-bias MFMAs.
__global__ __launch_bounds__(512) void scores2_kernel(float* __restrict__ ws)
{
    __shared__ unsigned short sAll[4096*8];   // units: 0..383 Q | 384..3967 K | 3968..4095 R
    __shared__ float sc[63][48];

    unsigned short* sQ = sAll;
    unsigned short* sK = sAll + 384*8;
    unsigned short* sR = sAll + 3968*8;

    const int bid = blockIdx.x;
    const int b = bid / 48, h = bid % 48;
    const int tid = threadIdx.x;
    const int wv = tid >> 6, ln = tid & 63;
    const int l15 = ln & 15, g4 = ln >> 4;
    const int key = l15 & 7;

    const unsigned short* QB = (const unsigned short*)ws;
    const unsigned short* KB = (const unsigned short*)(ws + KBOFF);
    const unsigned short* RB = (const unsigned short*)(ws + RBOFF);

    for (int u = tid; u < 63*48; u += 512) ((float*)sc)[u] = 0.f;

    const int dk = wv;                        // waves 0..6
    const int hp = h + dk - 3;
    const bool dok = (wv < 7) && (hp >= 0) && (hp < 48);

    f32x4 acc[6], qx[3], qy[3];
    #pragma unroll
    for (int i = 0; i < 6; ++i) acc[i] = (f32x4){0.f,0.f,0.f,0.f};
    #pragma unroll
    for (int i = 0; i < 3; ++i) { qx[i] = (f32x4){0.f,0.f,0.f,0.f}; qy[i] = (f32x4){0.f,0.f,0.f,0.f}; }

    for (int ck = 0; ck < 8; ++ck) {
        // ---- stage: 8 wave-issues each (64 units of 16B) ----
        #pragma unroll
        for (int e = 0; e < 8; ++e) {
            const int I = wv*8 + e;
            uint4* dst = (uint4*)sAll + I*64;               // wave-uniform base
            if (I < 6) {
                int unit = I*64 + ln; int row = unit >> 3, gr = unit & 7;
                const uint4* src = (const uint4*)QB
                    + ((((size_t)b*8 + ck)*48 + h)*48 + row)*8 + gr;
                gload16(src, dst);
            } else if (I < 62) {
                int uk = (I-6)*64 + ln;
                int kri = uk >> 9;                           // wave-uniform
                int wi = uk & 511; int row = wi >> 3, gr = wi & 7;
                int kh = h + kri - 3;
                if (kh >= 0 && kh < 48) {
                    const uint4* src = (const uint4*)KB
                        + ((((size_t)b*8 + ck)*48 + kh)*64 + row)*8 + gr;
                    gload16(src, dst);
                }
            } else {
                int ur = (I-62)*64 + ln; int row = ur >> 3, gr = ur & 7;
                int rel = ck >> 2, c4 = ck & 3;
                const uint4* src = (const uint4*)RB
                    + (((size_t)rel*4 + c4)*16 + row)*8 + gr;
                gload16(src, dst);
            }
        }
        __syncthreads();

        // ---- A frags (q) shared by all waves ----
        bf16x8 AH[3], AL[3];
        #pragma unroll
        for (int i = 0; i < 3; ++i) {
            const unsigned short* qr = sQ + (16*i + l15)*64;
            AH[i] = *(const bf16x8*)(qr + ((g4       ^ key)*8));
            AL[i] = *(const bf16x8*)(qr + (((g4 + 4) ^ key)*8));
        }

        if (wv < 7) {
            if (dok) {
                const unsigned short* kbase = sK + dk*4096;
                bf16x8 BH[4], BL[4];
                #pragma unroll
                for (int j = 0; j < 4; ++j) {
                    const unsigned short* kr = kbase + (j*16 + l15)*64;
                    BH[j] = *(const bf16x8*)(kr + ((g4       ^ key)*8));
                    BL[j] = *(const bf16x8*)(kr + (((g4 + 4) ^ key)*8));
                }
                #pragma unroll
                for (int i = 0; i < 3; ++i) {
                    acc[i*2]   = __builtin_amdgcn_mfma_f32_16x16x32_bf16(AH[i], BH[i],   acc[i*2],   0,0,0);
                    acc[i*2]   = __builtin_amdgcn_mfma_f32_16x16x32_bf16(AH[i], BL[i],   acc[i*2],   0,0,0);
                    acc[i*2]   = __builtin_amdgcn_mfma_f32_16x16x32_bf16(AL[i], BH[i],   acc[i*2],   0,0,0);
                    acc[i*2+1] = __builtin_amdgcn_mfma_f32_16x16x32_bf16(AH[i], BH[i+1], acc[i*2+1], 0,0,0);
                    acc[i*2+1] = __builtin_amdgcn_mfma_f32_16x16x32_bf16(AH[i], BL[i+1], acc[i*2+1], 0,0,0);
                    acc[i*2+1] = __builtin_amdgcn_mfma_f32_16x16x32_bf16(AL[i], BH[i+1], acc[i*2+1], 0,0,0);
                }
            }
        } else {
            const unsigned short* rr = sR + l15*64;
            bf16x8 RH = *(const bf16x8*)(rr + ((g4       ^ key)*8));
            bf16x8 RL = *(const bf16x8*)(rr + (((g4 + 4) ^ key)*8));
            if (ck < 4) {
                #pragma unroll
                for (int i = 0; i < 3; ++i) {
                    qx[i] = __builtin_amdgcn_mfma_f32_16x16x32_bf16(AH[i], RH, qx[i], 0,0,0);
                    qx[i] = __builtin_amdgcn_mfma_f32_16x16x32_bf16(AH[i], RL, qx[i], 0,0,0);
                    qx[i] = __builtin_amdgcn_mfma_f32_16x16x32_bf16(AL[i], RH, qx[i], 0,0,0);
                }
            } else {
                #pragma unroll
                for (int i = 0; i < 3; ++i) {
                    qy[i] = __builtin_amdgcn_mfma_f32_16x16x32_bf16(AH[i], RH, qy[i], 0,0,0);
                    qy[i] = __builtin_amdgcn_mfma_f32_16x16x32_bf16(AH[i], RL, qy[i], 0,0,0);
                    qy[i] = __builtin_amdgcn_mfma_f32_16x16x32_bf16(AL[i], RH, qy[i], 0,0,0);
                }
            }
        }
        __syncthreads();
    }

    // ---- band extraction: D row = 4*g4+reg (= w within tile), col = l15 (= kw idx) ----
    const int n = l15;
    if (wv < 7) {
        if (dok) {
            #pragma unroll
            for (int i = 0; i < 3; ++i)
                #pragma unroll
                for (int a = 0; a < 2; ++a) {
                    f32x4 A = acc[i*2+a];
                    #pragma unroll
                    for (int r = 0; r < 4; ++r) {
                        int m = 4*g4 + r;
                        int dl = n - m + a*16;
                        if (dl >= 0 && dl < 7)
                            sc[dk*7 + dl][16*i + m] = A[r];
                    }
                }
        }
    } else {
        if (n < 7) {
            #pragma unroll
            for (int i = 0; i < 3; ++i)
                #pragma unroll
                for (int r = 0; r < 4; ++r) {
                    sc[49 + n][16*i + 4*g4 + r] = qx[i][r];
                    sc[56 + n][16*i + 4*g4 + r] = qy[i][r];
                }
        }
    }
    __syncthreads();

    // ---- fused softmax (threads 0..47 = w) ----
    if (tid < 48) {
        const int w = tid;
        float tot[KK], rx[7], ry[7];
        #pragma unroll
        for (int i = 0; i < KK; ++i) tot[i] = sc[i][w];
        #pragma unroll
        for (int l = 0; l < 7; ++l) { rx[l] = sc[49+l][w]; ry[l] = sc[56+l][w]; }
        float mx = -1e30f;
        #pragma unroll
        for (int dk2 = 0; dk2 < 7; ++dk2)
            #pragma unroll
            for (int dl = 0; dl < 7; ++dl) {
                tot[dk2*7+dl] += ry[dk2] + rx[dl];
                mx = fmaxf(mx, tot[dk2*7+dl]);
            }
        float sum = 0.f;
        #pragma unroll
        for (int i = 0; i < KK; ++i) { float e = __expf(tot[i]-mx); tot[i]=e; sum += e; }
        float inv = 1.f/sum;
        float* base = ws + ATTNOFF + ((size_t)(b*HH + h)*64)*WW + w;
        #pragma unroll
        for (int i = 0; i < KK; ++i) base[(size_t)i*WW] = tot[i]*inv;
    }
}

// ---- PV + bias (unchanged R12 version) ----
__global__ __launch_bounds__(128) void pv_kernel(
    const float* __restrict__ bias,
    const float* __restrict__ ws,
    float* __restrict__ out)
{
    const float* vbuf = ws + (size_t)2*QSZ;
    const float* attn = ws + ATTNOFF;

    const int bid = blockIdx.x;
    const int pxt = bid % 18;
    const int pgq = (bid / 18) % 16;
    const int b   = bid / (18*16);

    const int tid = threadIdx.x;
    const int pxg = tid & 31;
    const int pg  = pgq*4 + (tid >> 5);

    const int hw0 = pxt*128 + pxg*4;
    const int w0 = hw0 % WW;
    const int h0 = hw0 / WW;

    const float* vb = vbuf + ((size_t)b*64 + pg)*HWHW*4;
    const float* ab = attn + ((size_t)(b*HH + h0)*64)*WW;

    const float4 b4 = *(const float4*)(bias + pg*4);
    f32x4 bias4 = (f32x4){b4.x, b4.y, b4.z, b4.w};
    f32x4 acc[4];
    #pragma unroll
    for (int p = 0; p < 4; ++p) acc[p] = bias4;

    #pragma unroll
    for (int dk = 0; dk < 7; ++dk) {
        const int gr = h0 + dk - 3;
        const bool rok = (gr >= 0 && gr < HH);
        f32x4 vrow[10];
        #pragma unroll
        for (int jj = 0; jj < 10; ++jj) {
            const int gc = w0 - 3 + jj;
            vrow[jj] = (rok && gc >= 0 && gc < WW)
                ? *(const f32x4*)(vb + ((size_t)gr*WW + gc)*4)
                : (f32x4){0.f,0.f,0.f,0.f};
        }
        const float* arow = ab + (size_t)(dk*7)*WW + w0;
        #pragma unroll
        for (int dl = 0; dl < 7; ++dl) {
            const float4 av = *(const float4*)(arow + (size_t)dl*WW);
            acc[0] += vrow[dl+0] * av.x;
            acc[1] += vrow[dl+1] * av.y;
            acc[2] += vrow[dl+2] * av.z;
            acc[3] += vrow[dl+3] * av.w;
        }
    }
    #pragma unroll
    for (int c = 0; c < 4; ++c) {
        float4 o;
        o.x = acc[0][c]; o.y = acc[1][c]; o.z = acc[2][c]; o.w = acc[3][c];
        *(float4*)(out + ((size_t)b*CC + pg*4 + c)*HWHW + hw0) = o;
    }
}

extern "C" void kernel_launch(void* const* d_in, const int* in_sizes, int n_in,
                              void* d_out, int out_size, void* d_ws, size_t ws_size,
                              hipStream_t stream) {
    const float* x    = (const float*)d_in[0];
    const float* wq   = (const float*)d_in[1];
    const float* wk   = (const float*)d_in[2];
    const float* wv   = (const float*)d_in[3];
    const float* bias = (const float*)d_in[4];
    const float* relx = (const float*)d_in[5];
    const float* rely = (const float*)d_in[6];
    float* ws  = (float*)d_ws;
    float* out = (float*)d_out;
    unsigned short* xt = (unsigned short*)d_out;
    unsigned short* wt = (unsigned short*)(ws + WTOFF);

    prep_kernel<<<dim3(1153), dim3(256), 0, stream>>>(x, wq, wk, wv, relx, rely, xt, wt, ws);
    proj_gemm_kernel<<<dim3(144, 12), dim3(256), 0, stream>>>(xt, wt, ws);
    scores2_kernel<<<dim3(BB*HH), dim3(512), 0, stream>>>(ws);
    pv_kernel<<<dim3(BB*16*18), dim3(128), 0, stream>>>(bias, ws, out);
}

// Round 16
// 74.911 us; speedup vs baseline: 1.1907x; 1.0032x over previous
//
#include <hip/hip_runtime.h>

#define BB 4
#define CC 256
#define HH 48
#define WW 48
#define HWHW 2304
#define KK 49
#define RELN 128

// ws float offsets: QB(bf16,swz) | (free) | v f32 | sbuf | WT | KB(bf16,swz) | RB
#define QSZ (BB*CC*HWHW)            // 2359296 floats
#define ATTNOFF (3*QSZ)             // sbuf: [B*H][64][48] taps 0..48
#define SBUF_FLOATS (BB*HH*64*WW)
#define WTOFF (ATTNOFF + SBUF_FLOATS)
#define WT_FLOATS 196608
#define KBOFF (WTOFF + WT_FLOATS)   // KB: 4b*8ck*48h*64row*64u16 = 3145728 floats
#define KB_FLOATS 3145728
#define RBOFF (KBOFF + KB_FLOATS)   // RB: 2rel*4ck*16l*64u16 = 4096 floats
// XT (bf16 hi/lo of x, pre-swizzled) lives in d_out

typedef short bf16x8 __attribute__((ext_vector_type(8)));
typedef float f32x4 __attribute__((ext_vector_type(4)));

__device__ __forceinline__ void split_bf16(float f, unsigned short& hi, unsigned short& lo)
{
    unsigned u = __float_as_uint(f);
    hi = (unsigned short)(u >> 16);
    float r = f - __uint_as_float(u & 0xFFFF0000u);
    unsigned v = __float_as_uint(r);
    v += 0x7FFFu + ((v >> 16) & 1u);
    lo = (unsigned short)(v >> 16);
}

__device__ __forceinline__ void gload16(const uint4* g, uint4* l)
{
    __builtin_amdgcn_global_load_lds(
        (const __attribute__((address_space(1))) void*)g,
        (__attribute__((address_space(3))) void*)l, 16, 0, 0);
}

// ---- prep: convert x->XT | w->WT | zero KB pad rows | build RB ----
__global__ __launch_bounds__(256) void prep_kernel(
    const float* __restrict__ x,
    const float* __restrict__ wq, const float* __restrict__ wk,
    const float* __restrict__ wvp,
    const float* __restrict__ relx, const float* __restrict__ rely,
    unsigned short* __restrict__ xt, unsigned short* __restrict__ wt,
    float* __restrict__ ws)
{
    __shared__ unsigned short lds[32*520];
    const int bid = blockIdx.x;
    const int t = threadIdx.x;

    if (bid < 288) {                       // convert_x
        const int b = bid / 72;
        const int hw0 = (bid % 72) * 32;
        const int hw = t & 31, cp = t >> 5;
        #pragma unroll 4
        for (int i = 0; i < 32; ++i) {
            int c = i*8 + cp;
            float f = x[((size_t)b*CC + c)*HWHW + hw0 + hw];
            unsigned short hi, lo; split_bf16(f, hi, lo);
            int ch = i*2;
            lds[hw*520 + ((ch       ^ (hw&7))*8) + cp] = hi;
            lds[hw*520 + (((ch + 1) ^ (hw&7))*8) + cp] = lo;
        }
        __syncthreads();
        const int hw2 = t >> 3, u = t & 7;
        uint4* xt4 = (uint4*)xt;
        const size_t rowbase = ((size_t)b*HWHW + hw0 + hw2) * 64;
        #pragma unroll
        for (int j = 0; j < 8; ++j) {
            int chunk = j*8 + u;
            uint4 v = *(const uint4*)&lds[hw2*520 + chunk*8];
            xt4[rowbase + chunk] = v;
        }
        return;
    }
    if (bid < 384) {                       // convert_w
        const int tt = (bid - 288)*256 + t;
        const int m = tt >> 5, kg = tt & 31;
        const float* src = (m < 256) ? wq : (m < 512) ? wk : wvp;
        const float* row = src + (size_t)(m & 255)*256 + kg*8;
        unsigned short h[8], l[8];
        #pragma unroll
        for (int j = 0; j < 8; ++j) split_bf16(row[j], h[j], l[j]);
        uint4 hv, lv;
        hv.x = (unsigned)h[0] | ((unsigned)h[1]<<16); hv.y = (unsigned)h[2] | ((unsigned)h[3]<<16);
        hv.z = (unsigned)h[4] | ((unsigned)h[5]<<16); hv.w = (unsigned)h[6] | ((unsigned)h[7]<<16);
        lv.x = (unsigned)l[0] | ((unsigned)l[1]<<16); lv.y = (unsigned)l[2] | ((unsigned)l[3]<<16);
        lv.z = (unsigned)l[4] | ((unsigned)l[5]<<16); lv.w = (unsigned)l[6] | ((unsigned)l[7]<<16);
        uint4* dstrow = (uint4*)wt + (size_t)m*64;
        const int ks = kg >> 2, s_hi = 2*(kg & 3);
        dstrow[ks*8 + ( s_hi      ^ (m&7))] = hv;
        dstrow[ks*8 + ((s_hi + 1) ^ (m&7))] = lv;
        return;
    }
    if (bid < 576) {                       // zero only KB PAD rows (w+3 outside [3,51))
        uint4* kb4 = (uint4*)(ws + KBOFF);
        const uint4 z = make_uint4(0u,0u,0u,0u);
        int u0 = (bid - 384)*256 + t;
        #pragma unroll
        for (int it = 0; it < 4; ++it) {
            int u = u0 + it*49152;         // 0..196607
            int bch = u >> 7, rem = u & 127;
            int r16 = rem >> 3, gr = rem & 7;
            int r = (r16 < 3) ? r16 : 48 + r16;
            kb4[((size_t)bch*64 + r)*8 + gr] = z;
        }
        return;
    }
    {                                       // RB: rel tables, bf16 hi/lo, swizzled
        unsigned short* rb = (unsigned short*)(ws + RBOFF);
        #pragma unroll
        for (int it = 0; it < 4; ++it) {
            int idx = t + it*256;
            int gi  = idx & 7;
            int l   = (idx >> 3) & 15;
            int ck4 = (idx >> 7) & 3;
            int rel = idx >> 9;
            int isLo = gi >> 2, g4i = gi & 3;
            unsigned short vals[8];
            #pragma unroll
            for (int j = 0; j < 8; ++j) {
                int cl = ck4*32 + g4i*8 + j;
                float f = (l < 7) ? (rel ? rely[cl*7 + l] : relx[cl*7 + l]) : 0.f;
                unsigned short hi, lo; split_bf16(f, hi, lo);
                vals[j] = isLo ? lo : hi;
            }
            int slot = gi ^ (l & 7);
            unsigned short* dst = rb + (((size_t)rel*4 + ck4)*16 + l)*64 + slot*8;
            uint4 pack;
            pack.x = (unsigned)vals[0] | ((unsigned)vals[1]<<16);
            pack.y = (unsigned)vals[2] | ((unsigned)vals[3]<<16);
            pack.z = (unsigned)vals[4] | ((unsigned)vals[5]<<16);
            pack.w = (unsigned)vals[6] | ((unsigned)vals[7]<<16);
            *(uint4*)dst = pack;
        }
    }
}

// ---- Projection GEMM: q,k -> bf16 QB/KB via LDS-staged COALESCED writes; v -> f32 ----
__global__ __launch_bounds__(256) void proj_gemm_kernel(
    const unsigned short* __restrict__ xt,
    const unsigned short* __restrict__ wt,
    float* __restrict__ ws)
{
    __shared__ uint4 smem[2][1024];
    const int n0 = blockIdx.x * 64;
    const int m0 = blockIdx.y * 64;
    const int b = n0 / HWHW;
    const int hwb = n0 % HWHW;
    const int tid = threadIdx.x;
    const int wid = tid >> 6, ln = tid & 63;
    const int wm = wid >> 1, wn = wid & 1;
    const int l15 = ln & 15, g = ln >> 4;

    f32x4 acc[2][2];
    #pragma unroll
    for (int i = 0; i < 2; ++i)
        #pragma unroll
        for (int j = 0; j < 2; ++j) acc[i][j] = (f32x4){0.f,0.f,0.f,0.f};

    const uint4* wt4 = (const uint4*)wt;
    const uint4* xt4 = (const uint4*)xt;
    const int lrow = ln >> 3, lslot = ln & 7;

    #define STAGE(bf, ks)                                                          \
        {                                                                          \
            _Pragma("unroll")                                                      \
            for (int i = 0; i < 2; ++i) {                                          \
                int seg = wid*2 + i;                                               \
                int row = seg*8 + lrow;                                            \
                gload16(wt4 + (size_t)(m0 + row)*64 + (ks)*8 + lslot,              \
                        &smem[bf][seg*64]);                                        \
                gload16(xt4 + (size_t)(n0 + row)*64 + (ks)*8 + lslot,              \
                        &smem[bf][512 + seg*64]);                                  \
            }                                                                      \
        }

    STAGE(0, 0);
    #pragma unroll
    for (int ks = 0; ks < 8; ++ks) {
        const int cur = ks & 1;
        if (ks < 7) STAGE(cur ^ 1, ks + 1);
        if (ks < 7) asm volatile("s_waitcnt vmcnt(4)" ::: "memory");
        else        asm volatile("s_waitcnt vmcnt(0)" ::: "memory");
        __builtin_amdgcn_s_barrier();
        __builtin_amdgcn_sched_barrier(0);
        bf16x8 aH[2], aL[2], bH[2], bL[2];
        #pragma unroll
        for (int mt = 0; mt < 2; ++mt) {
            int rA = wm*32 + mt*16 + l15;
            aH[mt] = *(const bf16x8*)&smem[cur][rA*8 + ((2*g)   ^ (rA&7))];
            aL[mt] = *(const bf16x8*)&smem[cur][rA*8 + ((2*g+1) ^ (rA&7))];
        }
        #pragma unroll
        for (int nt = 0; nt < 2; ++nt) {
            int rB = wn*32 + nt*16 + l15;
            bH[nt] = *(const bf16x8*)&smem[cur][512 + rB*8 + ((2*g)   ^ (rB&7))];
            bL[nt] = *(const bf16x8*)&smem[cur][512 + rB*8 + ((2*g+1) ^ (rB&7))];
        }
        #pragma unroll
        for (int mt = 0; mt < 2; ++mt)
            #pragma unroll
            for (int nt = 0; nt < 2; ++nt) {
                acc[mt][nt] = __builtin_amdgcn_mfma_f32_16x16x32_bf16(aH[mt], bH[nt], acc[mt][nt], 0, 0, 0);
                acc[mt][nt] = __builtin_amdgcn_mfma_f32_16x16x32_bf16(aH[mt], bL[nt], acc[mt][nt], 0, 0, 0);
                acc[mt][nt] = __builtin_amdgcn_mfma_f32_16x16x32_bf16(aL[mt], bH[nt], acc[mt][nt], 0, 0, 0);
            }
        if (ks < 7) {
            asm volatile("s_waitcnt lgkmcnt(0)" ::: "memory");
            __builtin_amdgcn_s_barrier();
        }
    }
    #undef STAGE

    const int proj = m0 >> 8;
    if (proj == 2) {
        #pragma unroll
        for (int mt = 0; mt < 2; ++mt) {
            int chb = (m0 & 255) + wm*32 + mt*16 + 4*g;
            int ch4 = chb >> 2;
            #pragma unroll
            for (int nt = 0; nt < 2; ++nt) {
                int hw = hwb + wn*32 + nt*16 + l15;
                float* dst = ws + (size_t)2*QSZ + (((size_t)b*64 + ch4)*HWHW + hw)*4;
                *(f32x4*)dst = acc[mt][nt];
            }
        }
        return;
    }
    // q/k: stage the 128-row x 128B output tile in LDS (final byte layout), then
    // copy out coalesced. Q: 2 contiguous 8KB segments. K: 128B-aligned rows.
    __syncthreads();                         // all smem reads of K-loop done
    unsigned short* eb = (unsigned short*)&smem[0][0];   // 16KB used
    #pragma unroll
    for (int mt = 0; mt < 2; ++mt) {
        const int chb = (m0 & 255) + wm*32 + mt*16 + 4*g;
        const int ckl = (chb >> 5) & 1;
        const int p = chb & 31, g8 = p >> 3, half = (p >> 2) & 1;
        #pragma unroll
        for (int nt = 0; nt < 2; ++nt) {
            const int hwl = wn*32 + nt*16 + l15;
            const int w = (hwb + hwl) % 48;
            const int key = (proj == 0 ? w : w + 3) & 7;
            f32x4 v = acc[mt][nt];
            unsigned short h0,h1,h2,h3,q0,q1,q2,q3;
            split_bf16(v[0],h0,q0); split_bf16(v[1],h1,q1);
            split_bf16(v[2],h2,q2); split_bf16(v[3],h3,q3);
            uint2 hv, lv;
            hv.x = (unsigned)h0 | ((unsigned)h1<<16); hv.y = (unsigned)h2 | ((unsigned)h3<<16);
            lv.x = (unsigned)q0 | ((unsigned)q1<<16); lv.y = (unsigned)q2 | ((unsigned)q3<<16);
            const int base = (ckl*64 + hwl)*64;
            *(uint2*)(eb + base + ((g8 ^ key)*8 + half*4))     = hv;
            *(uint2*)(eb + base + (((g8+4) ^ key)*8 + half*4)) = lv;
        }
    }
    __syncthreads();
    const int ck0 = (m0 & 255) >> 5;
    if (proj == 0) {
        const uint4* src = (const uint4*)eb;
        uint4* qb4 = (uint4*)ws;
        #pragma unroll
        for (int ckl2 = 0; ckl2 < 2; ++ckl2) {
            uint4* dst = qb4 + (((size_t)b*8 + ck0 + ckl2)*HWHW + hwb)*8;
            #pragma unroll
            for (int it = 0; it < 2; ++it)
                dst[tid + it*256] = src[ckl2*512 + tid + it*256];
        }
    } else {
        uint4* kb4 = (uint4*)(ws + KBOFF);
        const uint4* src = (const uint4*)eb;
        #pragma unroll
        for (int it = 0; it < 4; ++it) {
            int u = tid + it*256;
            int row = u >> 3, gr = u & 7;
            int ckl2 = row >> 6, hwl2 = row & 63;
            int hw2 = hwb + hwl2, h2 = hw2/48, w2 = hw2%48;
            uint4* dst = kb4 + ((((size_t)b*8 + ck0 + ckl2)*48 + h2)*64 + (w2+3))*8;
            dst[gr] = src[u];
        }
    }
}

// ---- scores2: banded MFMA + band extraction + fused softmax (unchanged R15) ----
__global__ __launch_bounds__(512) void scores2_kernel(float* __restrict__ ws)
{
    __shared__ unsigned short sAll[4096*8];
    __shared__ float sc[63][48];

    unsigned short* sQ = sAll;
    unsigned short* sK = sAll + 384*8;
    unsigned short* sR = sAll + 3968*8;

    const int bid = blockIdx.x;
    const int b = bid / 48, h = bid % 48;
    const int tid = threadIdx.x;
    const int wv = tid >> 6, ln = tid & 63;
    const int l15 = ln & 15, g4 = ln >> 4;
    const int key = l15 & 7;

    const unsigned short* QB = (const unsigned short*)ws;
    const unsigned short* KB = (const unsigned short*)(ws + KBOFF);
    const unsigned short* RB = (const unsigned short*)(ws + RBOFF);

    for (int u = tid; u < 63*48; u += 512) ((float*)sc)[u] = 0.f;

    const int dk = wv;
    const int hp = h + dk - 3;
    const bool dok = (wv < 7) && (hp >= 0) && (hp < 48);

    f32x4 acc[6], qx[3], qy[3];
    #pragma unroll
    for (int i = 0; i < 6; ++i) acc[i] = (f32x4){0.f,0.f,0.f,0.f};
    #pragma unroll
    for (int i = 0; i < 3; ++i) { qx[i] = (f32x4){0.f,0.f,0.f,0.f}; qy[i] = (f32x4){0.f,0.f,0.f,0.f}; }

    for (int ck = 0; ck < 8; ++ck) {
        #pragma unroll
        for (int e = 0; e < 8; ++e) {
            const int I = wv*8 + e;
            uint4* dst = (uint4*)sAll + I*64;
            if (I < 6) {
                int unit = I*64 + ln; int row = unit >> 3, gr = unit & 7;
                const uint4* src = (const uint4*)QB
                    + ((((size_t)b*8 + ck)*48 + h)*48 + row)*8 + gr;
                gload16(src, dst);
            } else if (I < 62) {
                int uk = (I-6)*64 + ln;
                int kri = uk >> 9;
                int wi = uk & 511; int row = wi >> 3, gr = wi & 7;
                int kh = h + kri - 3;
                if (kh >= 0 && kh < 48) {
                    const uint4* src = (const uint4*)KB
                        + ((((size_t)b*8 + ck)*48 + kh)*64 + row)*8 + gr;
                    gload16(src, dst);
                }
            } else {
                int ur = (I-62)*64 + ln; int row = ur >> 3, gr = ur & 7;
                int rel = ck >> 2, c4 = ck & 3;
                const uint4* src = (const uint4*)RB
                    + (((size_t)rel*4 + c4)*16 + row)*8 + gr;
                gload16(src, dst);
            }
        }
        __syncthreads();

        bf16x8 AH[3], AL[3];
        #pragma unroll
        for (int i = 0; i < 3; ++i) {
            const unsigned short* qr = sQ + (16*i + l15)*64;
            AH[i] = *(const bf16x8*)(qr + ((g4       ^ key)*8));
            AL[i] = *(const bf16x8*)(qr + (((g4 + 4) ^ key)*8));
        }

        if (wv < 7) {
            if (dok) {
                const unsigned short* kbase = sK + dk*4096;
                bf16x8 BH[4], BL[4];
                #pragma unroll
                for (int j = 0; j < 4; ++j) {
                    const unsigned short* kr = kbase + (j*16 + l15)*64;
                    BH[j] = *(const bf16x8*)(kr + ((g4       ^ key)*8));
                    BL[j] = *(const bf16x8*)(kr + (((g4 + 4) ^ key)*8));
                }
                #pragma unroll
                for (int i = 0; i < 3; ++i) {
                    acc[i*2]   = __builtin_amdgcn_mfma_f32_16x16x32_bf16(AH[i], BH[i],   acc[i*2],   0,0,0);
                    acc[i*2]   = __builtin_amdgcn_mfma_f32_16x16x32_bf16(AH[i], BL[i],   acc[i*2],   0,0,0);
                    acc[i*2]   = __builtin_amdgcn_mfma_f32_16x16x32_bf16(AL[i], BH[i],   acc[i*2],   0,0,0);
                    acc[i*2+1] = __builtin_amdgcn_mfma_f32_16x16x32_bf16(AH[i], BH[i+1], acc[i*2+1], 0,0,0);
                    acc[i*2+1] = __builtin_amdgcn_mfma_f32_16x16x32_bf16(AH[i], BL[i+1], acc[i*2+1], 0,0,0);
                    acc[i*2+1] = __builtin_amdgcn_mfma_f32_16x16x32_bf16(AL[i], BH[i+1], acc[i*2+1], 0,0,0);
                }
            }
        } else {
            const unsigned short* rr = sR + l15*64;
            bf16x8 RH = *(const bf16x8*)(rr + ((g4       ^ key)*8));
            bf16x8 RL = *(const bf16x8*)(rr + (((g4 + 4) ^ key)*8));
            if (ck < 4) {
                #pragma unroll
                for (int i = 0; i < 3; ++i) {
                    qx[i] = __builtin_amdgcn_mfma_f32_16x16x32_bf16(AH[i], RH, qx[i], 0,0,0);
                    qx[i] = __builtin_amdgcn_mfma_f32_16x16x32_bf16(AH[i], RL, qx[i], 0,0,0);
                    qx[i] = __builtin_amdgcn_mfma_f32_16x16x32_bf16(AL[i], RH, qx[i], 0,0,0);
                }
            } else {
                #pragma unroll
                for (int i = 0; i < 3; ++i) {
                    qy[i] = __builtin_amdgcn_mfma_f32_16x16x32_bf16(AH[i], RH, qy[i], 0,0,0);
                    qy[i] = __builtin_amdgcn_mfma_f32_16x16x32_bf16(AH[i], RL, qy[i], 0,0,0);
                    qy[i] = __builtin_amdgcn_mfma_f32_16x16x32_bf16(AL[i], RH, qy[i], 0,0,0);
                }
            }
        }
        __syncthreads();
    }

    const int n = l15;
    if (wv < 7) {
        if (dok) {
            #pragma unroll
            for (int i = 0; i < 3; ++i)
                #pragma unroll
                for (int a = 0; a < 2; ++a) {
                    f32x4 A = acc[i*2+a];
                    #pragma unroll
                    for (int r = 0; r < 4; ++r) {
                        int m = 4*g4 + r;
                        int dl = n - m + a*16;
                        if (dl >= 0 && dl < 7)
                            sc[dk*7 + dl][16*i + m] = A[r];
                    }
                }
        }
    } else {
        if (n < 7) {
            #pragma unroll
            for (int i = 0; i < 3; ++i)
                #pragma unroll
                for (int r = 0; r < 4; ++r) {
                    sc[49 + n][16*i + 4*g4 + r] = qx[i][r];
                    sc[56 + n][16*i + 4*g4 + r] = qy[i][r];
                }
        }
    }
    __syncthreads();

    if (tid < 48) {
        const int w = tid;
        float tot[KK], rx[7], ry[7];
        #pragma unroll
        for (int i = 0; i < KK; ++i) tot[i] = sc[i][w];
        #pragma unroll
        for (int l = 0; l < 7; ++l) { rx[l] = sc[49+l][w]; ry[l] = sc[56+l][w]; }
        float mx = -1e30f;
        #pragma unroll
        for (int dk2 = 0; dk2 < 7; ++dk2)
            #pragma unroll
            for (int dl = 0; dl < 7; ++dl) {
                tot[dk2*7+dl] += ry[dk2] + rx[dl];
                mx = fmaxf(mx, tot[dk2*7+dl]);
            }
        float sum = 0.f;
        #pragma unroll
        for (int i = 0; i < KK; ++i) { float e = __expf(tot[i]-mx); tot[i]=e; sum += e; }
        float inv = 1.f/sum;
        float* base = ws + ATTNOFF + ((size_t)(b*HH + h)*64)*WW + w;
        #pragma unroll
        for (int i = 0; i < KK; ++i) base[(size_t)i*WW] = tot[i]*inv;
    }
}

// ---- PV + bias (unchanged) ----
__global__ __launch_bounds__(128) void pv_kernel(
    const float* __restrict__ bias,
    const float* __restrict__ ws,
    float* __restrict__ out)
{
    const float* vbuf = ws + (size_t)2*QSZ;
    const float* attn = ws + ATTNOFF;

    const int bid = blockIdx.x;
    const int pxt = bid % 18;
    const int pgq = (bid / 18) % 16;
    const int b   = bid / (18*16);

    const int tid = threadIdx.x;
    const int pxg = tid & 31;
    const int pg  = pgq*4 + (tid >> 5);

    const int hw0 = pxt*128 + pxg*4;
    const int w0 = hw0 % WW;
    const int h0 = hw0 / WW;

    const float* vb = vbuf + ((size_t)b*64 + pg)*HWHW*4;
    const float* ab = attn + ((size_t)(b*HH + h0)*64)*WW;

    const float4 b4 = *(const float4*)(bias + pg*4);
    f32x4 bias4 = (f32x4){b4.x, b4.y, b4.z, b4.w};
    f32x4 acc[4];
    #pragma unroll
    for (int p = 0; p < 4; ++p) acc[p] = bias4;

    #pragma unroll
    for (int dk = 0; dk < 7; ++dk) {
        const int gr = h0 + dk - 3;
        const bool rok = (gr >= 0 && gr < HH);
        f32x4 vrow[10];
        #pragma unroll
        for (int jj = 0; jj < 10; ++jj) {
            const int gc = w0 - 3 + jj;
            vrow[jj] = (rok && gc >= 0 && gc < WW)
                ? *(const f32x4*)(vb + ((size_t)gr*WW + gc)*4)
                : (f32x4){0.f,0.f,0.f,0.f};
        }
        const float* arow = ab + (size_t)(dk*7)*WW + w0;
        #pragma unroll
        for (int dl = 0; dl < 7; ++dl) {
            const float4 av = *(const float4*)(arow + (size_t)dl*WW);
            acc[0] += vrow[dl+0] * av.x;
            acc[1] += vrow[dl+1] * av.y;
            acc[2] += vrow[dl+2] * av.z;
            acc[3] += vrow[dl+3] * av.w;
        }
    }
    #pragma unroll
    for (int c = 0; c < 4; ++c) {
        float4 o;
        o.x = acc[0][c]; o.y = acc[1][c]; o.z = acc[2][c]; o.w = acc[3][c];
        *(float4*)(out + ((size_t)b*CC + pg*4 + c)*HWHW + hw0) = o;
    }
}

extern "C" void kernel_launch(void* const* d_in, const int* in_sizes, int n_in,
                              void* d_out, int out_size, void* d_ws, size_t ws_size,
                              hipStream_t stream) {
    const float* x    = (const float*)d_in[0];
    const float* wq   = (const float*)d_in[1];
    const float* wk   = (const float*)d_in[2];
    const float* wv   = (const float*)d_in[3];
    const float* bias = (const float*)d_in[4];
    const float* relx = (const float*)d_in[5];
    const float* rely = (const float*)d_in[6];
    float* ws  = (float*)d_ws;
    float* out = (float*)d_out;
    unsigned short* xt = (unsigned short*)d_out;
    unsigned short* wt = (unsigned short*)(ws + WTOFF);

    prep_kernel<<<dim3(577), dim3(256), 0, stream>>>(x, wq, wk, wv, relx, rely, xt, wt, ws);
    proj_gemm_kernel<<<dim3(144, 12), dim3(256), 0, stream>>>(xt, wt, ws);
    scores2_kernel<<<dim3(BB*HH), dim3(512), 0, stream>>>(ws);
    pv_kernel<<<dim3(BB*16*18), dim3(128), 0, stream>>>(bias, ws, out);
}